// Round 16
// baseline (153.902 us; speedup 1.0000x reference)
//
#include <hip/hip_runtime.h>

#define VOCAB 50000
#define VDIM 256
#define TOPICS 512
#define VT 32
#define NBLK 1563   // ceil(VOCAB/VT)
#define NXCD 8

// Barrier with LDS-visibility only: does NOT drain vmcnt, so global stores
// stay in flight across phases (all inter-wave data in this kernel is LDS).
#define SYNC_LDS() asm volatile("s_waitcnt lgkmcnt(0)\n\ts_barrier" ::: "memory")

typedef unsigned int uint;
typedef unsigned short ushort;
using short8 = __attribute__((ext_vector_type(8))) short;
using f32x4  = __attribute__((ext_vector_type(4))) float;

__device__ __forceinline__ ushort bf16_rne(float f) {
  uint u = __float_as_uint(f);
  u += 0x7FFFu + ((u >> 16) & 1u);
  return (ushort)(u >> 16);
}
__device__ __forceinline__ float bf16f(ushort h) {
  return __uint_as_float(((uint)h) << 16);
}
__device__ __forceinline__ uint packbf2(float a, float b) {
  return (uint)bf16_rne(a) | ((uint)bf16_rne(b) << 16);
}

// Bijective chunked XCD swizzle (m204): consecutive logical ids -> same XCD.
__device__ __forceinline__ int xcd_swizzle(int orig, int nwg) {
  const int q = nwg / NXCD, r = nwg % NXCD;
  const int xcd = orig % NXCD, i = orig / NXCD;
  return (xcd < r ? xcd * (q + 1) : r * (q + 1) + (xcd - r) * q) + i;
}

// ---------------------------------------------------------------------------
// Precompute, single-plane bf16 fragment-major packing:
//   tBp[tile=t>>4][ks=d>>5][lane=(t&15)|(((d>>3)&3)<<4)][e=d&7]   (256 KB)
//   Atp[dtile=d>>4][ks=t>>5][lane=(d&15)|(((t>>3)&3)<<4)][e=t&7]  (256 KB)
// ---------------------------------------------------------------------------
__global__ __launch_bounds__(512) void precompute(
    const float* __restrict__ t2v, const float* __restrict__ A,
    const float* __restrict__ B,
    ushort* __restrict__ tBp, ushort* __restrict__ Atp)
{
  __shared__ float row[256];
  const int b = blockIdx.x, tid = threadIdx.x;
  if (b < TOPICS) {
    const int t = b;
    if (tid < 256) row[tid] = t2v[(size_t)t * 256 + tid];
    __syncthreads();
    if (tid < 256) {
      const int d = tid;
      const float4* rv = (const float4*)row;
      const float4* bv = (const float4*)(B + (size_t)d * 256);
      float acc = 0.f;
#pragma unroll 8
      for (int k = 0; k < 64; ++k) {
        float4 r = rv[k], x = bv[k];
        acc += r.x * x.x + r.y * x.y + r.z * x.z + r.w * x.w;
      }
      const int tile = t >> 4, ks = d >> 5;
      const int lane = (t & 15) | (((d >> 3) & 3) << 4);
      const int e = d & 7;
      tBp[((size_t)tile * 8 + ks) * 512 + lane * 8 + e] = bf16_rne(acc);
    }
  } else {
    const int d = b - TOPICS;
    if (tid < 256) row[tid] = A[(size_t)d * 256 + tid];
    __syncthreads();
    const int t = tid;
    const float4* rv = (const float4*)row;
    const float4* tv = (const float4*)(t2v + (size_t)t * 256);
    float acc = 0.f;
#pragma unroll 8
    for (int k = 0; k < 64; ++k) {
      float4 r = rv[k], x = tv[k];
      acc += r.x * x.x + r.y * x.y + r.z * x.z + r.w * x.w;
    }
    const int dtile = d >> 4, ks = t >> 5;
    const int lane = (d & 15) | (((t >> 3) & 3) << 4);
    const int e = t & 7;
    Atp[((size_t)dtile * 16 + ks) * 512 + lane * 8 + e] = bf16_rne(acc);
  }
}

// ---------------------------------------------------------------------------
// Fused main — R15 structure; ONLY change: all interior barriers are
// lgkm-only (SYNC_LDS), so global stores never drain at a barrier.
// ---------------------------------------------------------------------------
__global__ __launch_bounds__(256, 4) void fused_main(
    const float* __restrict__ w2v,
    const ushort* __restrict__ tBp, const ushort* __restrict__ Atp,
    const float* __restrict__ sigma,
    float* __restrict__ out_alpha, float* __restrict__ out_P,
    float* __restrict__ out_s,
    float* __restrict__ part_rs, float* __restrict__ part_ss, int do_rl)
{
  __shared__ __align__(16) char smem[33792];
  ushort (*Whi)[264] = (ushort (*)[264])smem;            // 16896 B
  ushort (*Wlo)[264] = (ushort (*)[264])(smem + 16896);  // 16896 B
  ushort (*PA)[520]  = (ushort (*)[520])smem;            // 33280 B (alias, W dead)
  float  (*SST)[32]  = (float  (*)[32])smem;             // 32768 B (alias, stage)
  __shared__ float red[4][VT];
  __shared__ float rs_lds[TOPICS];

  const int tid  = threadIdx.x;
  const int wave = tid >> 6, lane = tid & 63;
  const int lr = lane & 15, lg = lane >> 4;
  const int bid = xcd_swizzle(blockIdx.x, NBLK);
  const int vb = bid * VT;

  // ---- prefetch first 4 ring slots (steps 0..3) ----
  const ushort* sbase = tBp + (size_t)wave * 32768 + lane * 8;
  short8 Ah[4];
#pragma unroll
  for (int i = 0; i < 4; ++i)
    Ah[i] = *(const short8*)(sbase + (size_t)i * 4096);

  // ---- stage W hi/lo ----
#pragma unroll
  for (int it = 0; it < 8; ++it) {
    int j = tid + (it << 8);
    int v = j >> 6, q = j & 63;
    int vr = min(vb + v, VOCAB - 1);
    float4 x = *(const float4*)(w2v + (size_t)vr * 256 + (q << 2));
    float xs[4] = {x.x, x.y, x.z, x.w};
    ushort h[4], l[4];
#pragma unroll
    for (int i = 0; i < 4; ++i) {
      ushort hi = bf16_rne(xs[i]);
      h[i] = hi;
      l[i] = bf16_rne(xs[i] - bf16f(hi));
    }
    *(uint2*)&Whi[v][q << 2] = make_uint2((uint)h[0] | ((uint)h[1] << 16),
                                          (uint)h[2] | ((uint)h[3] << 16));
    *(uint2*)&Wlo[v][q << 2] = make_uint2((uint)l[0] | ((uint)l[1] << 16),
                                          (uint)l[2] | ((uint)l[3] << 16));
  }
  SYNC_LDS();

  // ---- s-GEMM: ring depth 4 steps, 4 MFMA/step ----
  f32x4 acc[8][2];
#pragma unroll
  for (int mi = 0; mi < 8; ++mi)
#pragma unroll
    for (int nj = 0; nj < 2; ++nj) acc[mi][nj] = (f32x4){0.f, 0.f, 0.f, 0.f};

#pragma unroll
  for (int ks = 0; ks < 8; ++ks) {
    const int k0 = (ks << 5) + (lg << 3);
    short8 bh[2], bl[2];
#pragma unroll
    for (int nj = 0; nj < 2; ++nj) {
      bh[nj] = *(const short8*)&Whi[(nj << 4) + lr][k0];
      bl[nj] = *(const short8*)&Wlo[(nj << 4) + lr][k0];
    }
#pragma unroll
    for (int mi = 0; mi < 8; ++mi) {
      const int n = (ks << 3) + mi;
      short8 ah = Ah[n & 3];
      if (n + 4 < 64) {
        const int n4 = n + 4;
        Ah[n & 3] = *(const short8*)(sbase + (size_t)(n4 & 7) * 4096
                                           + (size_t)(n4 >> 3) * 512);
      }
#pragma unroll
      for (int nj = 0; nj < 2; ++nj) {
        acc[mi][nj] = __builtin_amdgcn_mfma_f32_16x16x32_bf16(ah, bh[nj], acc[mi][nj], 0, 0, 0);
        acc[mi][nj] = __builtin_amdgcn_mfma_f32_16x16x32_bf16(ah, bl[nj], acc[mi][nj], 0, 0, 0);
      }
    }
  }
  SYNC_LDS();   // all waves done reading W; SST may overwrite it

  // ---- s store, vectorized: 2 phases of 256 rows each ----
#pragma unroll
  for (int ph = 0; ph < 2; ++ph) {
    if ((wave >> 1) == ph) {     // waves {0,1} stage phase 0; {2,3} phase 1
#pragma unroll
      for (int mi = 0; mi < 8; ++mi) {
        const int tb = ((wave & 1) << 7) + (mi << 4) + (lg << 2);
#pragma unroll
        for (int r = 0; r < 4; ++r) {
          const int t = tb + r, sw = (t & 7) << 2;
#pragma unroll
          for (int nj = 0; nj < 2; ++nj)
            SST[t][((nj << 4) + lr) ^ sw] = acc[mi][nj][r];
        }
      }
    }
    SYNC_LDS();
    {
      const int row = tid >> 3, cb = (tid & 7) << 2;
      const int v = vb + cb;
#pragma unroll
      for (int it = 0; it < 8; ++it) {
        const int t = row + (it << 5);
        if (v < VOCAB)
          *(float4*)(out_s + (size_t)(t + (ph << 8)) * VOCAB + v) =
              *(const float4*)&SST[t][cb ^ ((t & 7) << 2)];
      }
    }
    SYNC_LDS();
  }

  // ---- softmax max ----
  float gmax[2];
  {
    float pm[2] = {-3.4e38f, -3.4e38f};
#pragma unroll
    for (int mi = 0; mi < 8; ++mi)
#pragma unroll
      for (int nj = 0; nj < 2; ++nj)
#pragma unroll
        for (int r = 0; r < 4; ++r) pm[nj] = fmaxf(pm[nj], acc[mi][nj][r]);
#pragma unroll
    for (int nj = 0; nj < 2; ++nj) {
      pm[nj] = fmaxf(pm[nj], __shfl_xor(pm[nj], 16));
      pm[nj] = fmaxf(pm[nj], __shfl_xor(pm[nj], 32));
    }
    if (lg == 0) { red[wave][lr] = pm[0]; red[wave][16 + lr] = pm[1]; }
  }
  SYNC_LDS();
#pragma unroll
  for (int nj = 0; nj < 2; ++nj) {
    const int c = (nj << 4) + lr;
    gmax[nj] = fmaxf(fmaxf(red[0][c], red[1][c]), fmaxf(red[2][c], red[3][c]));
  }
  SYNC_LDS();

  // ---- prefetch first 4 mu ring slots; hide under exp pass ----
  const ushort* mbase = Atp + (size_t)wave * 32768 + lane * 8;
  short8 Mh[4];
#pragma unroll
  for (int i = 0; i < 4; ++i)
    Mh[i] = *(const short8*)(mbase + (size_t)i * 8192);

  float inv[2];
  {
    float ps[2] = {0.f, 0.f};
#pragma unroll
    for (int mi = 0; mi < 8; ++mi)
#pragma unroll
      for (int nj = 0; nj < 2; ++nj)
#pragma unroll
        for (int r = 0; r < 4; ++r) {
          float e = __expf(acc[mi][nj][r] - gmax[nj]);
          acc[mi][nj][r] = e;
          ps[nj] += e;
        }
#pragma unroll
    for (int nj = 0; nj < 2; ++nj) {
      ps[nj] += __shfl_xor(ps[nj], 16);
      ps[nj] += __shfl_xor(ps[nj], 32);
    }
    if (lg == 0) { red[wave][lr] = ps[0]; red[wave][16 + lr] = ps[1]; }
  }
  SYNC_LDS();
#pragma unroll
  for (int nj = 0; nj < 2; ++nj) {
    const int c = (nj << 4) + lr;
    inv[nj] = 1.0f / (red[0][c] + red[1][c] + red[2][c] + red[3][c]);
  }
  SYNC_LDS();

  // ---- scale acc -> alpha (registers) ----
#pragma unroll
  for (int mi = 0; mi < 8; ++mi)
#pragma unroll
    for (int nj = 0; nj < 2; ++nj)
#pragma unroll
      for (int r = 0; r < 4; ++r) acc[mi][nj][r] *= inv[nj];

  // ---- alpha store, vectorized (rows 128B-aligned) ----
#pragma unroll
  for (int ph = 0; ph < 2; ++ph) {
    if ((wave >> 1) == ph) {
#pragma unroll
      for (int mi = 0; mi < 8; ++mi) {
        const int tb = ((wave & 1) << 7) + (mi << 4) + (lg << 2);
#pragma unroll
        for (int r = 0; r < 4; ++r) {
          const int t = tb + r, sw = (t & 7) << 2;
#pragma unroll
          for (int nj = 0; nj < 2; ++nj)
            SST[t][((nj << 4) + lr) ^ sw] = acc[mi][nj][r];
        }
      }
    }
    SYNC_LDS();
    {
      const int row = tid >> 3, cb = (tid & 7) << 2;
      const int v = vb + cb;
#pragma unroll
      for (int it = 0; it < 8; ++it) {
        const int t = row + (it << 5);
        if (v < VOCAB)
          *(float4*)(out_alpha + (size_t)(t + (ph << 8)) * VOCAB + v) =
              *(const float4*)&SST[t][cb ^ ((t & 7) << 2)];
      }
    }
    SYNC_LDS();
  }

  // ---- PA bf16 (overwrites SST region) + RL partials ----
  float ssq = 0.f;
#pragma unroll
  for (int mi = 0; mi < 8; ++mi) {
    const int tb = (wave << 7) + (mi << 4) + (lg << 2);
#pragma unroll
    for (int nj = 0; nj < 2; ++nj) {
      uint2 pw;
      pw.x = packbf2(acc[mi][nj][0], acc[mi][nj][1]);
      pw.y = packbf2(acc[mi][nj][2], acc[mi][nj][3]);
      *(uint2*)&PA[(nj << 4) + lr][tb] = pw;
    }
    if (do_rl) {
#pragma unroll
      for (int r = 0; r < 4; ++r) {
        float rowp = 0.f;
#pragma unroll
        for (int nj = 0; nj < 2; ++nj) {
          float a = acc[mi][nj][r];
          float am = (vb + (nj << 4) + lr < VOCAB) ? a : 0.f;
          rowp += am;
          ssq = fmaf(am, am, ssq);
        }
        rowp += __shfl_xor(rowp, 1);
        rowp += __shfl_xor(rowp, 2);
        rowp += __shfl_xor(rowp, 4);
        rowp += __shfl_xor(rowp, 8);
        if (lr == 0) rs_lds[tb + r] = rowp;
      }
    }
  }
  SYNC_LDS();

  // ---- mu-GEMM: ring depth 4 steps, 2 MFMA/step ----
  f32x4 macc[4][2];
#pragma unroll
  for (int mi = 0; mi < 4; ++mi)
#pragma unroll
    for (int nj = 0; nj < 2; ++nj) macc[mi][nj] = (f32x4){0.f, 0.f, 0.f, 0.f};

#pragma unroll
  for (int ks = 0; ks < 16; ++ks) {
    const int k0 = (ks << 5) + (lg << 3);
    short8 pb[2];
#pragma unroll
    for (int nj = 0; nj < 2; ++nj)
      pb[nj] = *(const short8*)&PA[(nj << 4) + lr][k0];
#pragma unroll
    for (int mi = 0; mi < 4; ++mi) {
      const int n = (ks << 2) + mi;
      short8 ah = Mh[n & 3];
      if (n + 4 < 64) {
        const int n4 = n + 4;
        Mh[n & 3] = *(const short8*)(mbase + (size_t)(n4 & 3) * 8192
                                           + (size_t)(n4 >> 2) * 512);
      }
#pragma unroll
      for (int nj = 0; nj < 2; ++nj)
        macc[mi][nj] = __builtin_amdgcn_mfma_f32_16x16x32_bf16(ah, pb[nj], macc[mi][nj], 0, 0, 0);
    }
  }

  // ---- P: sum_d (w2v - mu)^2 per column (w2v re-read, L2/L3) ----
  {
    float pp[2] = {0.f, 0.f};
#pragma unroll
    for (int mi = 0; mi < 4; ++mi) {
      const int dbase = (wave << 6) + (mi << 4) + (lg << 2);
#pragma unroll
      for (int nj = 0; nj < 2; ++nj) {
        const int vr = min(vb + (nj << 4) + lr, VOCAB - 1);
        float4 w = *(const float4*)(w2v + (size_t)vr * 256 + dbase);
        float d0 = w.x - macc[mi][nj][0];
        float d1 = w.y - macc[mi][nj][1];
        float d2 = w.z - macc[mi][nj][2];
        float d3 = w.w - macc[mi][nj][3];
        pp[nj] += d0 * d0 + d1 * d1 + d2 * d2 + d3 * d3;
      }
    }
#pragma unroll
    for (int nj = 0; nj < 2; ++nj) {
      pp[nj] += __shfl_xor(pp[nj], 16);
      pp[nj] += __shfl_xor(pp[nj], 32);
    }
    if (lg == 0) { red[wave][lr] = pp[0]; red[wave][16 + lr] = pp[1]; }
  }
  SYNC_LDS();
  if (tid < VT) {
    float sum = red[0][tid] + red[1][tid] + red[2][tid] + red[3][tid];
    const int v = vb + tid;
    if (v < VOCAB) out_P[v] = sum / sigma[0];
  }

  // ---- coalesced part_rs block store (2KB contiguous) + ssq ----
  if (do_rl) {
    part_rs[(size_t)bid * TOPICS + tid]       = rs_lds[tid];
    part_rs[(size_t)bid * TOPICS + 256 + tid] = rs_lds[256 + tid];
    ssq += __shfl_xor(ssq, 1);
    ssq += __shfl_xor(ssq, 2);
    ssq += __shfl_xor(ssq, 4);
    ssq += __shfl_xor(ssq, 8);
    ssq += __shfl_xor(ssq, 16);
    ssq += __shfl_xor(ssq, 32);
    if (lane == 0) part_ss[bid * 4 + wave] = ssq;
  }
}

// ---------------------------------------------------------------------------
// RL pass 2: rowsum[t] = sum_blk part_rs[blk][t]. One block per topic.
// ---------------------------------------------------------------------------
__global__ __launch_bounds__(256) void rl_pass2(
    const float* __restrict__ part_rs, float* __restrict__ rowsum)
{
  const int t = blockIdx.x;
  float s = 0.f;
  for (int i = threadIdx.x; i < NBLK; i += 256)
    s += part_rs[(size_t)i * TOPICS + t];
  __shared__ float lsum[4];
  const int lane = threadIdx.x & 63, wave = threadIdx.x >> 6;
#pragma unroll
  for (int off = 32; off > 0; off >>= 1) s += __shfl_xor(s, off);
  if (lane == 0) lsum[wave] = s;
  __syncthreads();
  if (threadIdx.x == 0) rowsum[t] = lsum[0] + lsum[1] + lsum[2] + lsum[3];
}

__global__ __launch_bounds__(512) void rl_final_new(
    const float* __restrict__ rowsum, const float* __restrict__ part_ss,
    const float* __restrict__ sigma, float* __restrict__ out_RL,
    float* __restrict__ out_sigma)
{
  const int t = threadIdx.x;
  float b = rowsum[t] * rowsum[t];
  float a = 0.f;
  for (int i = t; i < NBLK * 4; i += 512) a += part_ss[i];
  __shared__ float la[8], lb[8];
  const int lane = t & 63, wave = t >> 6;
#pragma unroll
  for (int off = 32; off > 0; off >>= 1) {
    a += __shfl_xor(a, off);
    b += __shfl_xor(b, off);
  }
  if (lane == 0) { la[wave] = a; lb[wave] = b; }
  __syncthreads();
  if (t == 0) {
    float sa = 0.f, sb = 0.f;
#pragma unroll
    for (int w = 0; w < 8; ++w) { sa += la[w]; sb += lb[w]; }
    out_RL[0] = sa - sb / (float)VOCAB;
    out_sigma[0] = sigma[0];
  }
}

// ---------------------------------------------------------------------------
// Fallback (small ws): alpha re-read path
// ---------------------------------------------------------------------------
__global__ __launch_bounds__(256) void row_reduce(
    const float* __restrict__ alpha, float* __restrict__ rowsum, float* __restrict__ ssum)
{
  const int t = blockIdx.x;
  const float4* base = (const float4*)(alpha + (size_t)t * VOCAB);
  float rs = 0.f, ss = 0.f;
  for (int i = threadIdx.x; i < VOCAB / 4; i += 256) {
    float4 a = base[i];
    rs += a.x + a.y + a.z + a.w;
    ss += a.x * a.x + a.y * a.y + a.z * a.z + a.w * a.w;
  }
  __shared__ float lr[4], ls[4];
  const int lane = threadIdx.x & 63, wave = threadIdx.x >> 6;
#pragma unroll
  for (int off = 32; off > 0; off >>= 1) {
    rs += __shfl_xor(rs, off);
    ss += __shfl_xor(ss, off);
  }
  if (lane == 0) { lr[wave] = rs; ls[wave] = ss; }
  __syncthreads();
  if (threadIdx.x == 0) {
    rowsum[t] = lr[0] + lr[1] + lr[2] + lr[3];
    ssum[t]   = ls[0] + ls[1] + ls[2] + ls[3];
  }
}

__global__ __launch_bounds__(512) void rl_final_old(
    const float* __restrict__ rowsum, const float* __restrict__ ssum,
    const float* __restrict__ sigma, float* __restrict__ out_RL,
    float* __restrict__ out_sigma)
{
  const int t = threadIdx.x;
  float a = ssum[t];
  float b = rowsum[t] * rowsum[t];
  __shared__ float la[8], lb[8];
  const int lane = t & 63, wave = t >> 6;
#pragma unroll
  for (int off = 32; off > 0; off >>= 1) {
    a += __shfl_xor(a, off);
    b += __shfl_xor(b, off);
  }
  if (lane == 0) { la[wave] = a; lb[wave] = b; }
  __syncthreads();
  if (t == 0) {
    float sa = 0.f, sb = 0.f;
#pragma unroll
    for (int w = 0; w < 8; ++w) { sa += la[w]; sb += lb[w]; }
    out_RL[0] = sa - sb / (float)VOCAB;
    out_sigma[0] = sigma[0];
  }
}

extern "C" void kernel_launch(void* const* d_in, const int* in_sizes, int n_in,
                              void* d_out, int out_size, void* d_ws, size_t ws_size,
                              hipStream_t stream) {
  const float* w2v   = (const float*)d_in[0];  // [50000][256]
  const float* t2v   = (const float*)d_in[1];  // [512][256]
  const float* A     = (const float*)d_in[2];  // [256][256]
  const float* B     = (const float*)d_in[3];  // [256][256]
  const float* sigma = (const float*)d_in[4];  // [1]

  float* out       = (float*)d_out;
  float* out_alpha = out;                                  // 25,600,000
  float* out_P     = out + (size_t)TOPICS * VOCAB;         // 50,000
  float* out_RL    = out_P + VOCAB;                        // 1
  float* out_s     = out_RL + 1;                           // 25,600,000
  float* out_sigma = out_s + (size_t)TOPICS * VOCAB;       // 1

  ushort* tBp = (ushort*)d_ws;                             // 131072 ushorts (256 KB)
  ushort* Atp = tBp + (size_t)131072;                      // 131072 ushorts (256 KB)
  float* tail = (float*)(Atp + (size_t)131072);
  float* part_rs = tail;                                   // [NBLK][512]
  float* part_ss = part_rs + (size_t)NBLK * TOPICS;        // 1563*4
  float* rowsum  = part_ss + (size_t)NBLK * 4;             // 512
  size_t need = (size_t)(2 * 131072) * 2 +
                ((size_t)NBLK * TOPICS + (size_t)NBLK * 4 + TOPICS) * 4;
  const int do_rl = (ws_size >= need) ? 1 : 0;

  precompute<<<TOPICS + VDIM, 512, 0, stream>>>(t2v, A, B, tBp, Atp);

  fused_main<<<NBLK, 256, 0, stream>>>(w2v, tBp, Atp, sigma,
                                       out_alpha, out_P, out_s,
                                       part_rs, part_ss, do_rl);

  if (do_rl) {
    rl_pass2<<<TOPICS, 256, 0, stream>>>(part_rs, rowsum);
    rl_final_new<<<1, 512, 0, stream>>>(rowsum, part_ss, sigma, out_RL, out_sigma);
  } else {
    float* rs_old = tail;
    float* ss_old = rs_old + TOPICS;
    row_reduce<<<TOPICS, 256, 0, stream>>>(out_alpha, rs_old, ss_old);
    rl_final_old<<<1, 512, 0, stream>>>(rs_old, ss_old, sigma, out_RL, out_sigma);
  }
}

// Round 17
// 141.695 us; speedup vs baseline: 1.0861x; 1.0861x over previous
//
#include <hip/hip_runtime.h>

#define VOCAB 50000
#define VDIM 256
#define TOPICS 512
#define VT 64
#define NBLK 782     // ceil(VOCAB/64)
#define NXCD 8

// Barrier with LDS-visibility only (global stores stay in flight).
#define SYNC_LDS() asm volatile("s_waitcnt lgkmcnt(0)\n\ts_barrier" ::: "memory")

typedef unsigned int uint;
typedef unsigned short ushort;
using short8 = __attribute__((ext_vector_type(8))) short;
using f32x4  = __attribute__((ext_vector_type(4))) float;

__device__ __forceinline__ ushort bf16_rne(float f) {
  uint u = __float_as_uint(f);
  u += 0x7FFFu + ((u >> 16) & 1u);
  return (ushort)(u >> 16);
}
__device__ __forceinline__ float bf16f(ushort h) {
  return __uint_as_float(((uint)h) << 16);
}
__device__ __forceinline__ uint packbf2(float a, float b) {
  return (uint)bf16_rne(a) | ((uint)bf16_rne(b) << 16);
}

// Bijective chunked XCD swizzle (m204).
__device__ __forceinline__ int xcd_swizzle(int orig, int nwg) {
  const int q = nwg / NXCD, r = nwg % NXCD;
  const int xcd = orig % NXCD, i = orig / NXCD;
  return (xcd < r ? xcd * (q + 1) : r * (q + 1) + (xcd - r) * q) + i;
}

// ---------------------------------------------------------------------------
// Precompute, single-plane bf16 fragment-major packing (unchanged layout):
//   tBp[tile=t>>4][ks=d>>5][lane=(t&15)|(((d>>3)&3)<<4)][e=d&7]   (256 KB)
//   Atp[dtile=d>>4][ks=t>>5][lane=(d&15)|(((t>>3)&3)<<4)][e=t&7]  (256 KB)
// ---------------------------------------------------------------------------
__global__ __launch_bounds__(512) void precompute(
    const float* __restrict__ t2v, const float* __restrict__ A,
    const float* __restrict__ B,
    ushort* __restrict__ tBp, ushort* __restrict__ Atp)
{
  __shared__ float row[256];
  const int b = blockIdx.x, tid = threadIdx.x;
  if (b < TOPICS) {
    const int t = b;
    if (tid < 256) row[tid] = t2v[(size_t)t * 256 + tid];
    __syncthreads();
    if (tid < 256) {
      const int d = tid;
      const float4* rv = (const float4*)row;
      const float4* bv = (const float4*)(B + (size_t)d * 256);
      float acc = 0.f;
#pragma unroll 8
      for (int k = 0; k < 64; ++k) {
        float4 r = rv[k], x = bv[k];
        acc += r.x * x.x + r.y * x.y + r.z * x.z + r.w * x.w;
      }
      const int tile = t >> 4, ks = d >> 5;
      const int lane = (t & 15) | (((d >> 3) & 3) << 4);
      const int e = d & 7;
      tBp[((size_t)tile * 8 + ks) * 512 + lane * 8 + e] = bf16_rne(acc);
    }
  } else {
    const int d = b - TOPICS;
    if (tid < 256) row[tid] = A[(size_t)d * 256 + tid];
    __syncthreads();
    const int t = tid;
    const float4* rv = (const float4*)row;
    const float4* tv = (const float4*)(t2v + (size_t)t * 256);
    float acc = 0.f;
#pragma unroll 8
    for (int k = 0; k < 64; ++k) {
      float4 r = rv[k], x = tv[k];
      acc += r.x * x.x + r.y * x.y + r.z * x.z + r.w * x.w;
    }
    const int dtile = d >> 4, ks = t >> 5;
    const int lane = (d & 15) | (((t >> 3) & 3) << 4);
    const int e = t & 7;
    Atp[((size_t)dtile * 16 + ks) * 512 + lane * 8 + e] = bf16_rne(acc);
  }
}

// ---------------------------------------------------------------------------
// Fused main — VT=64, 512 threads / 8 waves; wave w owns t in [64w,64w+64)
// for the s-GEMM (all 64 cols) and d in [32w,32w+32) for mu. A-loads per
// output HALVED vs VT=32 (1:8 load:MFMA). Same per-thread register budget.
// ---------------------------------------------------------------------------
__global__ __launch_bounds__(512, 4) void fused_main(
    const float* __restrict__ w2v,
    const ushort* __restrict__ tBp, const ushort* __restrict__ Atp,
    const float* __restrict__ sigma,
    float* __restrict__ out_alpha, float* __restrict__ out_P,
    float* __restrict__ out_s,
    float* __restrict__ part_rs, float* __restrict__ part_ss, int do_rl)
{
  __shared__ __align__(16) char smem[67584];
  ushort (*Whi)[264] = (ushort (*)[264])smem;            // 64*264*2 = 33792 B
  ushort (*Wlo)[264] = (ushort (*)[264])(smem + 33792);  // 33792 B
  ushort (*PA)[520]  = (ushort (*)[520])smem;            // 66560 B (alias)
  float  (*SST)[66]  = (float  (*)[66])smem;             // 256*66*4 = 67584 B (alias)
  __shared__ float red[8][VT];                           // 2048 B
  __shared__ float rs_lds[TOPICS];                       // 2048 B

  const int tid  = threadIdx.x;
  const int wave = tid >> 6, lane = tid & 63;
  const int lr = lane & 15, lg = lane >> 4;
  const int bid = xcd_swizzle(blockIdx.x, NBLK);
  const int vb = bid * VT;

  // ---- prefetch first 4 s-ring slots (mi=0..3, ks=0) ----
  const ushort* sbase = tBp + (size_t)wave * 16384 + lane * 8;  // 4 tiles/wave
  short8 Ah[4];
#pragma unroll
  for (int i = 0; i < 4; ++i)
    Ah[i] = *(const short8*)(sbase + (size_t)i * 4096);

  // ---- stage W hi/lo (64 rows x 256 dims) ----
#pragma unroll
  for (int it = 0; it < 8; ++it) {
    int j = tid + (it << 9);
    int v = j >> 6, q = j & 63;
    int vr = min(vb + v, VOCAB - 1);
    float4 x = *(const float4*)(w2v + (size_t)vr * 256 + (q << 2));
    float xs[4] = {x.x, x.y, x.z, x.w};
    ushort h[4], l[4];
#pragma unroll
    for (int i = 0; i < 4; ++i) {
      ushort hi = bf16_rne(xs[i]);
      h[i] = hi;
      l[i] = bf16_rne(xs[i] - bf16f(hi));
    }
    *(uint2*)&Whi[v][q << 2] = make_uint2((uint)h[0] | ((uint)h[1] << 16),
                                          (uint)h[2] | ((uint)h[3] << 16));
    *(uint2*)&Wlo[v][q << 2] = make_uint2((uint)l[0] | ((uint)l[1] << 16),
                                          (uint)l[2] | ((uint)l[3] << 16));
  }
  SYNC_LDS();

  // ---- s-GEMM: acc[mi][nj]; 32 A-loads feed 256 MFMAs per wave ----
  f32x4 acc[4][4];
#pragma unroll
  for (int mi = 0; mi < 4; ++mi)
#pragma unroll
    for (int nj = 0; nj < 4; ++nj) acc[mi][nj] = (f32x4){0.f, 0.f, 0.f, 0.f};

#pragma unroll
  for (int ks = 0; ks < 8; ++ks) {
    const int k0 = (ks << 5) + (lg << 3);
    short8 bh[4], bl[4];
#pragma unroll
    for (int nj = 0; nj < 4; ++nj) {
      bh[nj] = *(const short8*)&Whi[(nj << 4) + lr][k0];
      bl[nj] = *(const short8*)&Wlo[(nj << 4) + lr][k0];
    }
#pragma unroll
    for (int mi = 0; mi < 4; ++mi) {
      short8 ah = Ah[mi];
      if (ks < 7)
        Ah[mi] = *(const short8*)(sbase + (size_t)mi * 4096
                                        + (size_t)(ks + 1) * 512);
#pragma unroll
      for (int nj = 0; nj < 4; ++nj) {
        acc[mi][nj] = __builtin_amdgcn_mfma_f32_16x16x32_bf16(ah, bh[nj], acc[mi][nj], 0, 0, 0);
        acc[mi][nj] = __builtin_amdgcn_mfma_f32_16x16x32_bf16(ah, bl[nj], acc[mi][nj], 0, 0, 0);
      }
    }
  }
  SYNC_LDS();   // W dead; SST may overwrite

  // ---- s store, vectorized: 2 phases of 256 rows (waves 0-3 / 4-7 stage) ----
#pragma unroll
  for (int ph = 0; ph < 2; ++ph) {
    if ((wave >> 2) == ph) {
#pragma unroll
      for (int mi = 0; mi < 4; ++mi) {
        const int tb = ((wave & 3) << 6) + (mi << 4) + (lg << 2);
#pragma unroll
        for (int r = 0; r < 4; ++r) {
          const int t = tb + r;
#pragma unroll
          for (int nj = 0; nj < 4; ++nj)
            SST[t][(nj << 4) + lr] = acc[mi][nj][r];
        }
      }
    }
    SYNC_LDS();
    {
      const int row = tid >> 4, cb = (tid & 15) << 2;
      const int v = vb + cb;
#pragma unroll
      for (int it = 0; it < 8; ++it) {
        const int t = row + (it << 5);
        if (v < VOCAB)
          *(float4*)(out_s + (size_t)(t + (ph << 8)) * VOCAB + v) =
              *(const float4*)&SST[t][cb];
      }
    }
    SYNC_LDS();
  }

  // ---- softmax max (per column over 512 topics; 8-wave combine) ----
  float gmax[4];
  {
    float pm[4] = {-3.4e38f, -3.4e38f, -3.4e38f, -3.4e38f};
#pragma unroll
    for (int mi = 0; mi < 4; ++mi)
#pragma unroll
      for (int nj = 0; nj < 4; ++nj)
#pragma unroll
        for (int r = 0; r < 4; ++r) pm[nj] = fmaxf(pm[nj], acc[mi][nj][r]);
#pragma unroll
    for (int nj = 0; nj < 4; ++nj) {
      pm[nj] = fmaxf(pm[nj], __shfl_xor(pm[nj], 16));
      pm[nj] = fmaxf(pm[nj], __shfl_xor(pm[nj], 32));
      if (lg == 0) red[wave][(nj << 4) + lr] = pm[nj];
    }
  }
  SYNC_LDS();
#pragma unroll
  for (int nj = 0; nj < 4; ++nj) {
    const int c = (nj << 4) + lr;
    float m0 = fmaxf(fmaxf(red[0][c], red[1][c]), fmaxf(red[2][c], red[3][c]));
    float m1 = fmaxf(fmaxf(red[4][c], red[5][c]), fmaxf(red[6][c], red[7][c]));
    gmax[nj] = fmaxf(m0, m1);
  }
  SYNC_LDS();

  // ---- prefetch first 4 mu ring slots (hide under exp) ----
  const ushort* mbase = Atp + (size_t)wave * 16384 + lane * 8;  // 2 dtiles/wave
  short8 Mh[4];
  Mh[0] = *(const short8*)(mbase);
  Mh[1] = *(const short8*)(mbase + 8192);
  Mh[2] = *(const short8*)(mbase + 512);
  Mh[3] = *(const short8*)(mbase + 8192 + 512);

  float inv[4];
  {
    float ps[4] = {0.f, 0.f, 0.f, 0.f};
#pragma unroll
    for (int mi = 0; mi < 4; ++mi)
#pragma unroll
      for (int nj = 0; nj < 4; ++nj)
#pragma unroll
        for (int r = 0; r < 4; ++r) {
          float e = __expf(acc[mi][nj][r] - gmax[nj]);
          acc[mi][nj][r] = e;
          ps[nj] += e;
        }
#pragma unroll
    for (int nj = 0; nj < 4; ++nj) {
      ps[nj] += __shfl_xor(ps[nj], 16);
      ps[nj] += __shfl_xor(ps[nj], 32);
      if (lg == 0) red[wave][(nj << 4) + lr] = ps[nj];
    }
  }
  SYNC_LDS();
#pragma unroll
  for (int nj = 0; nj < 4; ++nj) {
    const int c = (nj << 4) + lr;
    float s0 = (red[0][c] + red[1][c]) + (red[2][c] + red[3][c]);
    float s1 = (red[4][c] + red[5][c]) + (red[6][c] + red[7][c]);
    inv[nj] = 1.0f / (s0 + s1);
  }
  SYNC_LDS();

  // ---- scale acc -> alpha ----
#pragma unroll
  for (int mi = 0; mi < 4; ++mi)
#pragma unroll
    for (int nj = 0; nj < 4; ++nj)
#pragma unroll
      for (int r = 0; r < 4; ++r) acc[mi][nj][r] *= inv[nj];

  // ---- alpha store, vectorized (rows 128B-aligned) ----
#pragma unroll
  for (int ph = 0; ph < 2; ++ph) {
    if ((wave >> 2) == ph) {
#pragma unroll
      for (int mi = 0; mi < 4; ++mi) {
        const int tb = ((wave & 3) << 6) + (mi << 4) + (lg << 2);
#pragma unroll
        for (int r = 0; r < 4; ++r) {
          const int t = tb + r;
#pragma unroll
          for (int nj = 0; nj < 4; ++nj)
            SST[t][(nj << 4) + lr] = acc[mi][nj][r];
        }
      }
    }
    SYNC_LDS();
    {
      const int row = tid >> 4, cb = (tid & 15) << 2;
      const int v = vb + cb;
#pragma unroll
      for (int it = 0; it < 8; ++it) {
        const int t = row + (it << 5);
        if (v < VOCAB)
          *(float4*)(out_alpha + (size_t)(t + (ph << 8)) * VOCAB + v) =
              *(const float4*)&SST[t][cb];
      }
    }
    SYNC_LDS();
  }

  // ---- PA bf16 (overwrites SST region) + RL partials ----
  float ssq = 0.f;
#pragma unroll
  for (int mi = 0; mi < 4; ++mi) {
    const int tb = (wave << 6) + (mi << 4) + (lg << 2);
#pragma unroll
    for (int nj = 0; nj < 4; ++nj) {
      uint2 pw;
      pw.x = packbf2(acc[mi][nj][0], acc[mi][nj][1]);
      pw.y = packbf2(acc[mi][nj][2], acc[mi][nj][3]);
      *(uint2*)&PA[(nj << 4) + lr][tb] = pw;
    }
    if (do_rl) {
#pragma unroll
      for (int r = 0; r < 4; ++r) {
        float rowp = 0.f;
#pragma unroll
        for (int nj = 0; nj < 4; ++nj) {
          float a = acc[mi][nj][r];
          float am = (vb + (nj << 4) + lr < VOCAB) ? a : 0.f;
          rowp += am;
          ssq = fmaf(am, am, ssq);
        }
        rowp += __shfl_xor(rowp, 1);
        rowp += __shfl_xor(rowp, 2);
        rowp += __shfl_xor(rowp, 4);
        rowp += __shfl_xor(rowp, 8);
        if (lr == 0) rs_lds[tb + r] = rowp;
      }
    }
  }
  SYNC_LDS();

  // ---- mu-GEMM: wave owns d in [32w, 32w+32); 32 loads feed 128 MFMAs ----
  f32x4 macc[2][4];
#pragma unroll
  for (int mi = 0; mi < 2; ++mi)
#pragma unroll
    for (int nj = 0; nj < 4; ++nj) macc[mi][nj] = (f32x4){0.f, 0.f, 0.f, 0.f};

#pragma unroll
  for (int ks = 0; ks < 16; ++ks) {
    const int k0 = (ks << 5) + (lg << 3);
    short8 pb[4];
#pragma unroll
    for (int nj = 0; nj < 4; ++nj)
      pb[nj] = *(const short8*)&PA[(nj << 4) + lr][k0];
#pragma unroll
    for (int mi = 0; mi < 2; ++mi) {
      const int n = (ks << 1) + mi;
      short8 ah = Mh[n & 3];
      if (n + 4 < 32)
        Mh[n & 3] = *(const short8*)(mbase + (size_t)mi * 8192
                                           + (size_t)(ks + 2) * 512);
#pragma unroll
      for (int nj = 0; nj < 4; ++nj)
        macc[mi][nj] = __builtin_amdgcn_mfma_f32_16x16x32_bf16(ah, pb[nj], macc[mi][nj], 0, 0, 0);
    }
  }

  // ---- P: sum_d (w2v - mu)^2 per column (w2v re-read, L2/L3) ----
  {
    float pp[4] = {0.f, 0.f, 0.f, 0.f};
#pragma unroll
    for (int mi = 0; mi < 2; ++mi) {
      const int dbase = ((wave << 1) + mi) * 16 + (lg << 2);
#pragma unroll
      for (int nj = 0; nj < 4; ++nj) {
        const int vr = min(vb + (nj << 4) + lr, VOCAB - 1);
        float4 w = *(const float4*)(w2v + (size_t)vr * 256 + dbase);
        float d0 = w.x - macc[mi][nj][0];
        float d1 = w.y - macc[mi][nj][1];
        float d2 = w.z - macc[mi][nj][2];
        float d3 = w.w - macc[mi][nj][3];
        pp[nj] += d0 * d0 + d1 * d1 + d2 * d2 + d3 * d3;
      }
    }
#pragma unroll
    for (int nj = 0; nj < 4; ++nj) {
      pp[nj] += __shfl_xor(pp[nj], 16);
      pp[nj] += __shfl_xor(pp[nj], 32);
      if (lg == 0) red[wave][(nj << 4) + lr] = pp[nj];
    }
  }
  SYNC_LDS();
  if (tid < VT) {
    float s0 = (red[0][tid] + red[1][tid]) + (red[2][tid] + red[3][tid]);
    float s1 = (red[4][tid] + red[5][tid]) + (red[6][tid] + red[7][tid]);
    const int v = vb + tid;
    if (v < VOCAB) out_P[v] = (s0 + s1) / sigma[0];
  }

  // ---- coalesced part_rs block store (2KB contiguous) + ssq ----
  if (do_rl) {
    part_rs[(size_t)bid * TOPICS + tid] = rs_lds[tid];
    ssq += __shfl_xor(ssq, 1);
    ssq += __shfl_xor(ssq, 2);
    ssq += __shfl_xor(ssq, 4);
    ssq += __shfl_xor(ssq, 8);
    ssq += __shfl_xor(ssq, 16);
    ssq += __shfl_xor(ssq, 32);
    if (lane == 0) part_ss[bid * 8 + wave] = ssq;
  }
}

// ---------------------------------------------------------------------------
// RL pass 2: rowsum[t] = sum_blk part_rs[blk][t]. One block per topic.
// ---------------------------------------------------------------------------
__global__ __launch_bounds__(256) void rl_pass2(
    const float* __restrict__ part_rs, float* __restrict__ rowsum)
{
  const int t = blockIdx.x;
  float s = 0.f;
  for (int i = threadIdx.x; i < NBLK; i += 256)
    s += part_rs[(size_t)i * TOPICS + t];
  __shared__ float lsum[4];
  const int lane = threadIdx.x & 63, wave = threadIdx.x >> 6;
#pragma unroll
  for (int off = 32; off > 0; off >>= 1) s += __shfl_xor(s, off);
  if (lane == 0) lsum[wave] = s;
  __syncthreads();
  if (threadIdx.x == 0) rowsum[t] = lsum[0] + lsum[1] + lsum[2] + lsum[3];
}

__global__ __launch_bounds__(512) void rl_final_new(
    const float* __restrict__ rowsum, const float* __restrict__ part_ss,
    const float* __restrict__ sigma, float* __restrict__ out_RL,
    float* __restrict__ out_sigma)
{
  const int t = threadIdx.x;
  float b = rowsum[t] * rowsum[t];
  float a = 0.f;
  for (int i = t; i < NBLK * 8; i += 512) a += part_ss[i];
  __shared__ float la[8], lb[8];
  const int lane = t & 63, wave = t >> 6;
#pragma unroll
  for (int off = 32; off > 0; off >>= 1) {
    a += __shfl_xor(a, off);
    b += __shfl_xor(b, off);
  }
  if (lane == 0) { la[wave] = a; lb[wave] = b; }
  __syncthreads();
  if (t == 0) {
    float sa = 0.f, sb = 0.f;
#pragma unroll
    for (int w = 0; w < 8; ++w) { sa += la[w]; sb += lb[w]; }
    out_RL[0] = sa - sb / (float)VOCAB;
    out_sigma[0] = sigma[0];
  }
}

// ---------------------------------------------------------------------------
// Fallback (small ws): alpha re-read path
// ---------------------------------------------------------------------------
__global__ __launch_bounds__(256) void row_reduce(
    const float* __restrict__ alpha, float* __restrict__ rowsum, float* __restrict__ ssum)
{
  const int t = blockIdx.x;
  const float4* base = (const float4*)(alpha + (size_t)t * VOCAB);
  float rs = 0.f, ss = 0.f;
  for (int i = threadIdx.x; i < VOCAB / 4; i += 256) {
    float4 a = base[i];
    rs += a.x + a.y + a.z + a.w;
    ss += a.x * a.x + a.y * a.y + a.z * a.z + a.w * a.w;
  }
  __shared__ float lr[4], ls[4];
  const int lane = threadIdx.x & 63, wave = threadIdx.x >> 6;
#pragma unroll
  for (int off = 32; off > 0; off >>= 1) {
    rs += __shfl_xor(rs, off);
    ss += __shfl_xor(ss, off);
  }
  if (lane == 0) { lr[wave] = rs; ls[wave] = ss; }
  __syncthreads();
  if (threadIdx.x == 0) {
    rowsum[t] = lr[0] + lr[1] + lr[2] + lr[3];
    ssum[t]   = ls[0] + ls[1] + ls[2] + ls[3];
  }
}

__global__ __launch_bounds__(512) void rl_final_old(
    const float* __restrict__ rowsum, const float* __restrict__ ssum,
    const float* __restrict__ sigma, float* __restrict__ out_RL,
    float* __restrict__ out_sigma)
{
  const int t = threadIdx.x;
  float a = ssum[t];
  float b = rowsum[t] * rowsum[t];
  __shared__ float la[8], lb[8];
  const int lane = t & 63, wave = t >> 6;
#pragma unroll
  for (int off = 32; off > 0; off >>= 1) {
    a += __shfl_xor(a, off);
    b += __shfl_xor(b, off);
  }
  if (lane == 0) { la[wave] = a; lb[wave] = b; }
  __syncthreads();
  if (t == 0) {
    float sa = 0.f, sb = 0.f;
#pragma unroll
    for (int w = 0; w < 8; ++w) { sa += la[w]; sb += lb[w]; }
    out_RL[0] = sa - sb / (float)VOCAB;
    out_sigma[0] = sigma[0];
  }
}

extern "C" void kernel_launch(void* const* d_in, const int* in_sizes, int n_in,
                              void* d_out, int out_size, void* d_ws, size_t ws_size,
                              hipStream_t stream) {
  const float* w2v   = (const float*)d_in[0];  // [50000][256]
  const float* t2v   = (const float*)d_in[1];  // [512][256]
  const float* A     = (const float*)d_in[2];  // [256][256]
  const float* B     = (const float*)d_in[3];  // [256][256]
  const float* sigma = (const float*)d_in[4];  // [1]

  float* out       = (float*)d_out;
  float* out_alpha = out;                                  // 25,600,000
  float* out_P     = out + (size_t)TOPICS * VOCAB;         // 50,000
  float* out_RL    = out_P + VOCAB;                        // 1
  float* out_s     = out_RL + 1;                           // 25,600,000
  float* out_sigma = out_s + (size_t)TOPICS * VOCAB;       // 1

  ushort* tBp = (ushort*)d_ws;                             // 131072 ushorts (256 KB)
  ushort* Atp = tBp + (size_t)131072;                      // 131072 ushorts (256 KB)
  float* tail = (float*)(Atp + (size_t)131072);
  float* part_rs = tail;                                   // [NBLK][512]
  float* part_ss = part_rs + (size_t)NBLK * TOPICS;        // NBLK*8
  float* rowsum  = part_ss + (size_t)NBLK * 8;             // 512
  size_t need = (size_t)(2 * 131072) * 2 +
                ((size_t)NBLK * TOPICS + (size_t)NBLK * 8 + TOPICS) * 4;
  const int do_rl = (ws_size >= need) ? 1 : 0;

  precompute<<<TOPICS + VDIM, 512, 0, stream>>>(t2v, A, B, tBp, Atp);

  fused_main<<<NBLK, 512, 0, stream>>>(w2v, tBp, Atp, sigma,
                                       out_alpha, out_P, out_s,
                                       part_rs, part_ss, do_rl);

  if (do_rl) {
    rl_pass2<<<TOPICS, 256, 0, stream>>>(part_rs, rowsum);
    rl_final_new<<<1, 512, 0, stream>>>(rowsum, part_ss, sigma, out_RL, out_sigma);
  } else {
    float* rs_old = tail;
    float* ss_old = rs_old + TOPICS;
    row_reduce<<<TOPICS, 256, 0, stream>>>(out_alpha, rs_old, ss_old);
    rl_final_old<<<1, 512, 0, stream>>>(rs_old, ss_old, sigma, out_RL, out_sigma);
  }
}